// Round 4
// baseline (326.093 us; speedup 1.0000x reference)
//
#include <hip/hip_runtime.h>

#define BB 8
#define CC 64
#define HH 128
#define WW 128
#define TT 3
#define LL 4
#define MM 3

#define PW 130                    // padded spatial dim
#define IMGH ((size_t)PW * PW * CC)   // halves per padded image

typedef _Float16 half8 __attribute__((ext_vector_type(8)));
typedef _Float16 half4 __attribute__((ext_vector_type(4)));
typedef float floatx16 __attribute__((ext_vector_type(16)));

__device__ __forceinline__ void async_ld16(const _Float16* g, _Float16* l) {
    __builtin_amdgcn_global_load_lds(
        (const __attribute__((address_space(1))) void*)g,
        (__attribute__((address_space(3))) void*)l, 16, 0, 0);
}

// ---------------------------------------------------------------------------
// Weight prep (+ inline routing): every block recomputes the trivial argmax
// chain for its task, then gathers the selected module, fp32 -> fp16,
// rearranged to A-frag order:
// W3[tl][tap][c(2)][il(2)][o(2)][lane(64)*8] -- one a-frag = contiguous 1 KB.
// ---------------------------------------------------------------------------
__global__ __launch_bounds__(256) void prep_weights(
    const float* __restrict__ enc_w, // [L][M][64][64][3][3]
    const float* __restrict__ alpha0,
    const float* __restrict__ alphas,
    const float* __restrict__ g0,
    const float* __restrict__ gs,
    int* __restrict__ sel,           // [T][L]
    _Float16* __restrict__ W3)       // [12][36864]
{
    int tl = blockIdx.y;
    int t = tl >> 2, layer = tl & 3;
    int idx = 0;
    for (int l = 0; l <= layer; ++l) {
        const float *a, *g;
        if (l == 0) { a = alpha0 + t * MM; g = g0 + t * MM; }
        else {
            int off = (((l - 1) * TT + t) * MM + idx) * MM;
            a = alphas + off; g = gs + off;
        }
        float best = a[0] + g[0];
        int bi = 0;
        for (int j = 1; j < MM; ++j) {
            float v = a[j] + g[j];
            if (v > best) { best = v; bi = j; }
        }
        idx = bi;
    }
    const int m = idx;
    if (blockIdx.x == 0 && threadIdx.x == 0) sel[tl] = m;

    const float* src = enc_w + ((size_t)layer * MM + m) * (CC * CC * 9);
    _Float16* dst = W3 + (size_t)tl * 36864;
    for (int i = blockIdx.x * 256 + threadIdx.x; i < 36864; i += gridDim.x * 256) {
        int j   = i & 7;
        int l   = (i >> 3) & 63;
        int o   = (i >> 9) & 1;
        int il  = (i >> 10) & 1;
        int c   = (i >> 11) & 1;
        int tap = i >> 12;                      // 0..8
        int oc  = o * 32 + (l & 31);
        int kch = c * 32 + il * 16 + (l >> 5) * 8 + j;
        dst[i] = (_Float16)src[(oc * CC + kch) * 9 + tap];
    }
}

// ---------------------------------------------------------------------------
// Zero the 1-px borders of padded NHWC images (contiguous buffers).
// ---------------------------------------------------------------------------
__global__ __launch_bounds__(256) void zero_borders(_Float16* __restrict__ base0)
{
    _Float16* base = base0 + (size_t)blockIdx.x * IMGH;
    const int i0 = blockIdx.y * 1032;
    for (int i = i0 + threadIdx.x; i < i0 + 1032; i += 256) {
        int px_idx = i >> 3, q = i & 7;   // 516 border px * 8 half8-chunks
        int row, col;
        if (px_idx < 130)      { row = 0;            col = px_idx; }
        else if (px_idx < 260) { row = 129;          col = px_idx - 130; }
        else if (px_idx < 388) { row = px_idx - 259; col = 0; }
        else                   { row = px_idx - 387; col = 129; }
        half8 z = {};
        *(half8*)(base + ((size_t)row * PW + col) * CC + q * 8) = z;
    }
}

// ---------------------------------------------------------------------------
// x: NCHW fp32 -> padded NHWC f16 (interior). Lane = px, LDS transpose.
// ---------------------------------------------------------------------------
__global__ __launch_bounds__(256) void to_nhwc(
    const float* __restrict__ x,    // [B][64][128][128]
    _Float16* __restrict__ act0)    // [B][130][130][64] padded
{
    const int xs = blockIdx.x;  // 0..1
    const int y  = blockIdx.y;  // 0..127
    const int b  = blockIdx.z;  // 0..7

    __shared__ _Float16 lds[64 * 72];  // [px][ch], pad 72

    const int wv = threadIdx.x >> 6;
    const int l  = threadIdx.x & 63;
    const float* src = x + ((size_t)b * CC * HH + y) * WW + xs * 64 + l;
#pragma unroll
    for (int k = 0; k < 16; ++k) {
        int ch = wv * 16 + k;
        lds[l * 72 + ch] = (_Float16)src[(size_t)ch * HH * WW];
    }
    __syncthreads();
    int px = threadIdx.x >> 2;
    int q  = threadIdx.x & 3;
    _Float16* dst = act0 + (size_t)b * IMGH
                  + ((size_t)(y + 1) * PW + xs * 64 + px + 1) * CC + q * 16;
    *(half8*)dst       = *(const half8*)&lds[px * 72 + q * 16];
    *(half8*)(dst + 8) = *(const half8*)&lds[px * 72 + q * 16 + 8];
}

// ---------------------------------------------------------------------------
// 3x3 SAME conv + bias + ReLU on padded NHWC f16, MFMA 32x32x16.
// Block 256 thr / 4 waves; tile = 8 rows x 64 px x 64 oc; wave = 2 rows.
// K split into 4 phases of 16 ch (c x il).  BOTH act (2x21.5KB) and weights
// (2x18.4KB) double-buffered: phase p issues global_load_lds for phase p+1,
// then computes phase p from LDS; the trailing __syncthreads (implicit
// vmcnt(0)) retires loads that drained under ~1.5K cycles of compute.
// Memory requests stay outstanding through the whole kernel (fixes the
// 50% HBM duty cycle seen in r3: stage/compute were serial).
// Act LDS: [row][px][2 x 16B], slot s16 holds ch-half s16^((px>>2)&1) --
// conflict-free ds_read_b128 (every 8 consecutive lanes hit 8 bank-quads).
// LDS 79,872 B -> 2 blocks/CU.
// ---------------------------------------------------------------------------
__global__ __launch_bounds__(256, 2) void conv3x3_mfma(
    const _Float16* __restrict__ in,   // padded NHWC per task (stride tsi halves)
    _Float16* __restrict__ out,        // padded NHWC per task (stride tso halves)
    const _Float16* __restrict__ W3,   // [12][36864]
    const float* __restrict__ enc_b,   // [L][M][64]
    const int* __restrict__ sel,
    int layer, int task0, size_t tsi, size_t tso)
{
    const int y0  = (blockIdx.x >> 1) * 8;   // padded row of halo top
    const int px0 = (blockIdx.x & 1) * 64;   // padded col of halo left
    const int b   = blockIdx.y;
    const int tz  = blockIdx.z;
    const int t   = task0 + tz;

    const _Float16* inp = in + (size_t)tz * tsi + (size_t)b * IMGH;
    _Float16* outp      = out + (size_t)tz * tso + (size_t)b * IMGH;
    const int tl = t * LL + layer;
    const _Float16* Wt = W3 + (size_t)tl * 36864;

    const int tid  = threadIdx.x;
    const int lane = tid & 63;
    const int w    = tid >> 6;        // wave id; rows 2w, 2w+1 of the 8
    const int n    = lane & 31;
    const int ksub = lane >> 5;

    // act buf: 660 px-slots x 32B + pad = 21504B each (10752 halves)
    // wt buf : 18 frags x 1KB = 18432B each (9216 halves)   total 79872B
    __shared__ __align__(16) _Float16 lds[2 * 10752 + 2 * 9216];
    _Float16* actb0 = lds;
    _Float16* actb1 = lds + 10752;
    _Float16* wtb0  = lds + 21504;
    _Float16* wtb1  = lds + 21504 + 9216;

    floatx16 acc[2][2][2];   // [rr][o][h]
#pragma unroll
    for (int rr = 0; rr < 2; ++rr)
#pragma unroll
        for (int o = 0; o < 2; ++o)
#pragma unroll
            for (int j = 0; j < 2; ++j)
#pragma unroll
                for (int i = 0; i < 16; ++i) acc[rr][o][j][i] = 0.f;

    // b-frag read offsets (halves) per [dx][h]; il-independent
    int preoff[3][2];
#pragma unroll
    for (int dx = 0; dx < 3; ++dx)
#pragma unroll
        for (int h = 0; h < 2; ++h) {
            int pxv = dx + n + 32 * h;
            preoff[dx][h] = pxv * 16 + ((ksub ^ ((pxv >> 2) & 1)) << 3);
        }

    // ---- stage one 16-ch phase (act 21 ops + wt 18 ops) into buffer bp ----
#define STAGE(p, actd, wtd)                                                    \
    {                                                                          \
        const int c_ = (p) >> 1, il_ = (p) & 1;                                \
        for (int j = w; j < 21; j += 4) {                                      \
            int si = j * 64 + lane;          /* 16B slot 0..1343 */            \
            int s16 = si & 1;                                                  \
            int u = si >> 1;                 /* px-slot */                     \
            if (u > 659) u = 659;            /* tail dups -> LDS pad */        \
            int r = (u * 993) >> 16;         /* u/66, exact for u<660 */       \
            int px = u - r * 66;                                               \
            int ch = c_ * 32 + il_ * 16 + ((s16 ^ ((px >> 2) & 1)) << 3);      \
            const _Float16* src =                                              \
                inp + ((size_t)(y0 + r) * PW + (px0 + px)) * CC + ch;          \
            async_ld16(src, (actd) + j * 512);                                 \
        }                                                                      \
        for (int k = w; k < 18; k += 4) {                                      \
            const _Float16* src =                                              \
                Wt + ((k >> 1) * 8 + c_ * 4 + il_ * 2 + (k & 1)) * 512         \
                   + lane * 8;                                                 \
            async_ld16(src, (wtd) + k * 512);                                  \
        }                                                                      \
    }

    // ---- compute one phase from buffers (al, wl) ----
#define COMPUTE(al, wl)                                                        \
    {                                                                          \
        _Pragma("unroll")                                                      \
        for (int tap = 0; tap < 9; ++tap) {                                    \
            const int dy = tap / 3;                                            \
            const int dx = tap - dy * 3;                                       \
            half8 a0 = *(const half8*)((wl) + (tap * 2 + 0) * 512 + lane * 8); \
            half8 a1 = *(const half8*)((wl) + (tap * 2 + 1) * 512 + lane * 8); \
            _Pragma("unroll")                                                  \
            for (int rr = 0; rr < 2; ++rr) {                                   \
                const _Float16* lb = (al) + (2 * w + rr + dy) * 1056;          \
                half8 b0 = *(const half8*)(lb + preoff[dx][0]);                \
                half8 b1 = *(const half8*)(lb + preoff[dx][1]);                \
                acc[rr][0][0] = __builtin_amdgcn_mfma_f32_32x32x16_f16(a0, b0, acc[rr][0][0], 0, 0, 0); \
                acc[rr][0][1] = __builtin_amdgcn_mfma_f32_32x32x16_f16(a0, b1, acc[rr][0][1], 0, 0, 0); \
                acc[rr][1][0] = __builtin_amdgcn_mfma_f32_32x32x16_f16(a1, b0, acc[rr][1][0], 0, 0, 0); \
                acc[rr][1][1] = __builtin_amdgcn_mfma_f32_32x32x16_f16(a1, b1, acc[rr][1][1], 0, 0, 0); \
            }                                                                  \
        }                                                                      \
    }

    STAGE(0, actb0, wtb0);
    __syncthreads();                       // phase-0 buffers ready

    STAGE(1, actb1, wtb1);                 // in flight during compute(0)
    __builtin_amdgcn_sched_barrier(0);
    COMPUTE(actb0, wtb0);
    __syncthreads();                       // drains stage(1)

    STAGE(2, actb0, wtb0);
    __builtin_amdgcn_sched_barrier(0);
    COMPUTE(actb1, wtb1);
    __syncthreads();                       // drains stage(2)

    STAGE(3, actb1, wtb1);
    __builtin_amdgcn_sched_barrier(0);
    COMPUTE(actb0, wtb0);
    __syncthreads();                       // drains stage(3)

    COMPUTE(actb1, wtb1);
#undef STAGE
#undef COMPUTE

    // ---- epilogue: bias + ReLU -> padded NHWC f16 interior ----
    int m = sel[t * LL + layer];
    m = __builtin_amdgcn_readfirstlane(m);
    const float* Bp = enc_b + ((size_t)layer * MM + m) * CC;
#pragma unroll
    for (int rr = 0; rr < 2; ++rr) {
        _Float16* orow = outp + ((size_t)(y0 + 2 * w + rr + 1) * PW + 1) * CC;
#pragma unroll
        for (int o = 0; o < 2; ++o)
#pragma unroll
            for (int j = 0; j < 2; ++j) {
                int px = px0 + j * 32 + n;
                _Float16* po = orow + (size_t)px * CC;
#pragma unroll
                for (int rg = 0; rg < 4; ++rg) {
                    int oc = o * 32 + 4 * ksub + 8 * rg;
                    half4 h;
#pragma unroll
                    for (int k = 0; k < 4; ++k)
                        h[k] = (_Float16)fmaxf(acc[rr][o][j][rg * 4 + k] + Bp[oc + k], 0.f);
                    *(half4*)(po + oc) = h;
                }
            }
    }
}

// ---------------------------------------------------------------------------
// Decoder: 1x1 conv 64 -> 3 (+bias), L2-normalize for task 2. Padded NHWC in.
// ---------------------------------------------------------------------------
__global__ __launch_bounds__(256) void decoder_kernel(
    const _Float16* __restrict__ in, // padded NHWC f16, per-task stride ts halves
    size_t ts,
    const float* __restrict__ dec_w, // [T][3][64]
    const float* __restrict__ dec_b, // [T][3]
    float* __restrict__ out,         // [T][B][3][H][W]
    int task0, int ntask)
{
    const int HW = HH * WW;
    int gid = blockIdx.x * 256 + threadIdx.x;
    if (gid >= ntask * BB * HW) return;
    int tz = gid / (BB * HW);
    int rem = gid - tz * (BB * HW);
    int b = rem / HW;
    int px = rem - b * HW;
    int t = task0 + tz;
    int y = px >> 7;
    int xx = px & 127;

    const _Float16* hp = in + (size_t)tz * ts + (size_t)b * IMGH
                       + ((size_t)(y + 1) * PW + xx + 1) * CC;
    const float* w = dec_w + (size_t)t * 3 * CC;

    float a0 = dec_b[t * 3 + 0];
    float a1 = dec_b[t * 3 + 1];
    float a2 = dec_b[t * 3 + 2];
#pragma unroll
    for (int cc = 0; cc < CC; cc += 8) {
        half8 h = *(const half8*)(hp + cc);
#pragma unroll
        for (int k = 0; k < 8; ++k) {
            float v = (float)h[k];
            a0 += v * w[cc + k];
            a1 += v * w[CC + cc + k];
            a2 += v * w[2 * CC + cc + k];
        }
    }
    if (t == 2) {
        float r = 1.0f / sqrtf(a0 * a0 + a1 * a1 + a2 * a2);
        a0 *= r; a1 *= r; a2 *= r;
    }
    float* ob = out + ((size_t)t * BB + b) * 3 * HW + px;
    ob[0]      = a0;
    ob[HW]     = a1;
    ob[2 * HW] = a2;
}

extern "C" void kernel_launch(void* const* d_in, const int* in_sizes, int n_in,
                              void* d_out, int out_size, void* d_ws, size_t ws_size,
                              hipStream_t stream) {
    const float* x      = (const float*)d_in[0];
    const float* alpha0 = (const float*)d_in[1];
    const float* alphas = (const float*)d_in[2];
    const float* g0     = (const float*)d_in[3];
    const float* gs     = (const float*)d_in[4];
    const float* enc_w  = (const float*)d_in[5];
    const float* enc_b  = (const float*)d_in[6];
    const float* dec_w  = (const float*)d_in[7];
    const float* dec_b  = (const float*)d_in[8];
    float* out = (float*)d_out;

    const size_t ACT = (size_t)BB * IMGH;      // halves per padded activation buffer
    char* pw = (char*)d_ws;
    int* sel = (int*)pw;                 pw += 1024;
    _Float16* W3 = (_Float16*)pw;        pw += (size_t)12 * 36864 * 2;
    _Float16* act0 = (_Float16*)pw;      pw += ACT * 2;
    _Float16* bufs = (_Float16*)pw;
    size_t base = (size_t)(pw - (char*)d_ws);
    bool fused = ws_size >= base + 6 * ACT * 2;

    prep_weights<<<dim3(36, 12), 256, 0, stream>>>(enc_w, alpha0, alphas, g0, gs, sel, W3);
    int nbuf = fused ? 7 : 3;
    zero_borders<<<dim3(nbuf * BB, 4), 256, 0, stream>>>(act0);
    to_nhwc<<<dim3(2, HH, BB), 256, 0, stream>>>(x, act0);

    if (fused) {
        _Float16* A = bufs;        // task stride 2*ACT
        _Float16* B = bufs + ACT;  // task stride 2*ACT
        size_t ts = 2 * ACT;
        conv3x3_mfma<<<dim3(32, BB, 3), 256, 0, stream>>>(act0, A, W3, enc_b, sel, 0, 0, 0,  ts);
        conv3x3_mfma<<<dim3(32, BB, 3), 256, 0, stream>>>(A,    B, W3, enc_b, sel, 1, 0, ts, ts);
        conv3x3_mfma<<<dim3(32, BB, 3), 256, 0, stream>>>(B,    A, W3, enc_b, sel, 2, 0, ts, ts);
        conv3x3_mfma<<<dim3(32, BB, 3), 256, 0, stream>>>(A,    B, W3, enc_b, sel, 3, 0, ts, ts);
        decoder_kernel<<<(3 * BB * HH * WW + 255) / 256, 256, 0, stream>>>(
            B, ts, dec_w, dec_b, out, 0, 3);
    } else {
        _Float16* A = bufs;
        _Float16* B = bufs + ACT;
        for (int t = 0; t < TT; ++t) {
            conv3x3_mfma<<<dim3(32, BB, 1), 256, 0, stream>>>(act0, A, W3, enc_b, sel, 0, t, 0, 0);
            conv3x3_mfma<<<dim3(32, BB, 1), 256, 0, stream>>>(A,    B, W3, enc_b, sel, 1, t, 0, 0);
            conv3x3_mfma<<<dim3(32, BB, 1), 256, 0, stream>>>(B,    A, W3, enc_b, sel, 2, t, 0, 0);
            conv3x3_mfma<<<dim3(32, BB, 1), 256, 0, stream>>>(A,    B, W3, enc_b, sel, 3, t, 0, 0);
            decoder_kernel<<<(BB * HH * WW + 255) / 256, 256, 0, stream>>>(
                B, 0, dec_w, dec_b, out, t, 1);
        }
    }
}

// Round 5
// 241.213 us; speedup vs baseline: 1.3519x; 1.3519x over previous
//
#include <hip/hip_runtime.h>

#define BB 8
#define CC 64
#define HH 128
#define WW 128
#define TT 3
#define LL 4
#define MM 3

#define PW 130                         // padded spatial dim
#define CHP ((size_t)PW * PW * 16)     // halves per 16-ch chunk plane
#define IMGH ((size_t)PW * PW * CC)    // halves per padded image (= 4*CHP)

typedef _Float16 half8 __attribute__((ext_vector_type(8)));
typedef _Float16 half4 __attribute__((ext_vector_type(4)));
typedef float floatx16 __attribute__((ext_vector_type(16)));

__device__ __forceinline__ void async_ld16(const _Float16* g, _Float16* l) {
    __builtin_amdgcn_global_load_lds(
        (const __attribute__((address_space(1))) void*)g,
        (__attribute__((address_space(3))) void*)l, 16, 0, 0);
}

// ---------------------------------------------------------------------------
// Weight prep (+ inline routing): every block recomputes the argmax chain,
// gathers the selected module, fp32 -> fp16, A-frag order:
// W3[tl][tap][c(2)][il(2)][o(2)][lane(64)*8] -- one a-frag = contiguous 1 KB.
// ---------------------------------------------------------------------------
__global__ __launch_bounds__(256) void prep_weights(
    const float* __restrict__ enc_w, // [L][M][64][64][3][3]
    const float* __restrict__ alpha0,
    const float* __restrict__ alphas,
    const float* __restrict__ g0,
    const float* __restrict__ gs,
    int* __restrict__ sel,           // [T][L]
    _Float16* __restrict__ W3)       // [12][36864]
{
    int tl = blockIdx.y;
    int t = tl >> 2, layer = tl & 3;
    int idx = 0;
    for (int l = 0; l <= layer; ++l) {
        const float *a, *g;
        if (l == 0) { a = alpha0 + t * MM; g = g0 + t * MM; }
        else {
            int off = (((l - 1) * TT + t) * MM + idx) * MM;
            a = alphas + off; g = gs + off;
        }
        float best = a[0] + g[0];
        int bi = 0;
        for (int j = 1; j < MM; ++j) {
            float v = a[j] + g[j];
            if (v > best) { best = v; bi = j; }
        }
        idx = bi;
    }
    const int m = idx;
    if (blockIdx.x == 0 && threadIdx.x == 0) sel[tl] = m;

    const float* src = enc_w + ((size_t)layer * MM + m) * (CC * CC * 9);
    _Float16* dst = W3 + (size_t)tl * 36864;
    for (int i = blockIdx.x * 256 + threadIdx.x; i < 36864; i += gridDim.x * 256) {
        int j   = i & 7;
        int l   = (i >> 3) & 63;
        int o   = (i >> 9) & 1;
        int il  = (i >> 10) & 1;
        int c   = (i >> 11) & 1;
        int tap = i >> 12;                      // 0..8
        int oc  = o * 32 + (l & 31);
        int kch = c * 32 + il * 16 + (l >> 5) * 8 + j;
        dst[i] = (_Float16)src[(oc * CC + kch) * 9 + tap];
    }
}

// ---------------------------------------------------------------------------
// Zero the 1-px borders of chunk-plane padded images.
// ---------------------------------------------------------------------------
__global__ __launch_bounds__(256) void zero_borders(_Float16* __restrict__ base0)
{
    _Float16* base = base0 + (size_t)blockIdx.x * IMGH;
    const int i0 = blockIdx.y * 1032;
    for (int i = i0 + threadIdx.x; i < i0 + 1032; i += 256) {
        // 4128 half8 items: plane(4) x 516 border px x 2
        int pl  = i / 1032;
        int rem = i - pl * 1032;
        int px_idx = rem >> 1, sh = rem & 1;
        int row, col;
        if (px_idx < 130)      { row = 0;            col = px_idx; }
        else if (px_idx < 260) { row = 129;          col = px_idx - 130; }
        else if (px_idx < 388) { row = px_idx - 259; col = 0; }
        else                   { row = px_idx - 387; col = 129; }
        half8 z = {};
        *(half8*)(base + (size_t)pl * CHP + ((size_t)row * PW + col) * 16 + sh * 8) = z;
    }
}

// ---------------------------------------------------------------------------
// x: NCHW fp32 -> chunk-plane padded f16: [B][4][130*130][16] (interior).
// Lane = px (coalesced 256 B loads), LDS transpose; wave = one 16-ch plane.
// ---------------------------------------------------------------------------
__global__ __launch_bounds__(256) void to_chunked(
    const float* __restrict__ x,    // [B][64][128][128]
    _Float16* __restrict__ act0)
{
    const int xs = blockIdx.x;  // 0..1
    const int y  = blockIdx.y;  // 0..127
    const int b  = blockIdx.z;  // 0..7

    __shared__ _Float16 lds[64 * 72];  // [px][ch], pad 72

    const int wv = threadIdx.x >> 6;
    const int l  = threadIdx.x & 63;
    const float* src = x + ((size_t)b * CC * HH + y) * WW + xs * 64 + l;
#pragma unroll
    for (int k = 0; k < 16; ++k) {
        int ch = wv * 16 + k;
        lds[l * 72 + ch] = (_Float16)src[(size_t)ch * HH * WW];
    }
    __syncthreads();
    int px = threadIdx.x & 63;
    int q  = threadIdx.x >> 6;      // plane
    _Float16* dst = act0 + (size_t)b * IMGH + (size_t)q * CHP
                  + ((size_t)(y + 1) * PW + xs * 64 + px + 1) * 16;
    *(half8*)dst       = *(const half8*)&lds[px * 72 + q * 16];
    *(half8*)(dst + 8) = *(const half8*)&lds[px * 72 + q * 16 + 8];
}

// ---------------------------------------------------------------------------
// 3x3 SAME conv + bias + ReLU, chunk-plane f16 layout, MFMA 32x32x16.
// Block 256 thr / 4 waves; tile = 8 rows x 64 px x 64 oc; wave = 2 rows.
// K split into 4 phases of 16 ch = one chunk PLANE each: every fetched
// 128B line is fully consumed by one phase of one block (fixes r4's 1.5x
// over-fetch and r3's L2-thrash re-fetch).  Act (2x21.5KB) and weights
// (2x18.4KB) double-buffered; phase p issues global_load_lds for p+1 then
// computes p; trailing __syncthreads retires loads that had a full compute
// phase to drain.  LDS 79,872 B -> 2 blocks/CU.  Bijective chunked XCD
// swizzle keeps row-neighbor tiles (shared halo) and W3 on one XCD.
// ---------------------------------------------------------------------------
__global__ __launch_bounds__(256, 2) void conv3x3_mfma(
    const _Float16* __restrict__ in,   // chunked padded, per task stride tsi
    _Float16* __restrict__ out,        // chunked padded, per task stride tso
    const _Float16* __restrict__ W3,   // [12][36864]
    const float* __restrict__ enc_b,   // [L][M][64]
    const int* __restrict__ sel,
    int layer, int task0, size_t tsi, size_t tso)
{
    // ---- bijective chunked XCD swizzle over the flattened grid ----
    const int nwg  = gridDim.x * gridDim.y * gridDim.z;   // 768 (fused) / 256
    const int flat = blockIdx.x + gridDim.x * (blockIdx.y + gridDim.y * blockIdx.z);
    const int q8   = nwg >> 3;
    const int logical = (flat & 7) * q8 + (flat >> 3);
    const int bx  = logical & 31;          // gridDim.x == 32
    const int rem = logical >> 5;
    const int b   = rem & 7;               // gridDim.y == 8
    const int tz  = rem >> 3;

    const int y0  = (bx >> 1) * 8;   // padded row of halo top
    const int px0 = (bx & 1) * 64;   // padded col of halo left
    const int t   = task0 + tz;

    const _Float16* inp = in + (size_t)tz * tsi + (size_t)b * IMGH;
    _Float16* outp      = out + (size_t)tz * tso + (size_t)b * IMGH;
    const int tl = t * LL + layer;
    const _Float16* Wt = W3 + (size_t)tl * 36864;

    const int tid  = threadIdx.x;
    const int lane = tid & 63;
    const int w    = tid >> 6;        // wave id; rows 2w, 2w+1 of the 8
    const int n    = lane & 31;
    const int ksub = lane >> 5;

    // act buf: 1320 slots x 16B + pad = 21504B each (10752 halves)
    // wt buf : 18 frags x 1KB = 18432B each (9216 halves)    total 79872B
    __shared__ __align__(16) _Float16 lds[2 * 10752 + 2 * 9216];
    _Float16* actb0 = lds;
    _Float16* actb1 = lds + 10752;
    _Float16* wtb0  = lds + 21504;
    _Float16* wtb1  = lds + 21504 + 9216;

    floatx16 acc[2][2][2];   // [rr][o][j]
#pragma unroll
    for (int rr = 0; rr < 2; ++rr)
#pragma unroll
        for (int o = 0; o < 2; ++o)
#pragma unroll
            for (int j = 0; j < 2; ++j)
#pragma unroll
                for (int i = 0; i < 16; ++i) acc[rr][o][j][i] = 0.f;

    // b-frag read offsets (halves) per [dx][h]
    int preoff[3][2];
#pragma unroll
    for (int dx = 0; dx < 3; ++dx)
#pragma unroll
        for (int h = 0; h < 2; ++h) {
            int pxv = dx + n + 32 * h;
            preoff[dx][h] = pxv * 16 + ((ksub ^ ((pxv >> 2) & 1)) << 3);
        }

    // ---- stage one plane-phase (act 21 ops + wt 18 ops) ----
#define STAGE(p, actd, wtd)                                                    \
    {                                                                          \
        const _Float16* plane = inp + (size_t)(p) * CHP;                       \
        for (int j = w; j < 21; j += 4) {                                      \
            int si = j * 64 + lane;          /* 16B slot 0..1343 */            \
            int s16 = si & 1;                                                  \
            int u = si >> 1;                 /* px-slot */                     \
            if (u > 659) u = 659;            /* tail dups -> LDS pad */        \
            int r = (u * 993) >> 16;         /* u/66, exact for u<660 */       \
            int px = u - r * 66;                                               \
            const _Float16* src =                                              \
                plane + ((size_t)(y0 + r) * PW + (px0 + px)) * 16              \
                      + ((s16 ^ ((px >> 2) & 1)) << 3);                        \
            async_ld16(src, (actd) + j * 512);                                 \
        }                                                                      \
        const int c_ = (p) >> 1, il_ = (p) & 1;                                \
        for (int k = w; k < 18; k += 4) {                                      \
            const _Float16* src =                                              \
                Wt + ((k >> 1) * 8 + c_ * 4 + il_ * 2 + (k & 1)) * 512         \
                   + lane * 8;                                                 \
            async_ld16(src, (wtd) + k * 512);                                  \
        }                                                                      \
    }

    // ---- compute one phase from buffers (al, wl) ----
#define COMPUTE(al, wl)                                                        \
    {                                                                          \
        __builtin_amdgcn_s_setprio(1);                                         \
        _Pragma("unroll")                                                      \
        for (int tap = 0; tap < 9; ++tap) {                                    \
            const int dy = tap / 3;                                            \
            const int dx = tap - dy * 3;                                       \
            half8 a0 = *(const half8*)((wl) + (tap * 2 + 0) * 512 + lane * 8); \
            half8 a1 = *(const half8*)((wl) + (tap * 2 + 1) * 512 + lane * 8); \
            _Pragma("unroll")                                                  \
            for (int rr = 0; rr < 2; ++rr) {                                   \
                const _Float16* lb = (al) + (2 * w + rr + dy) * 1056;          \
                half8 b0 = *(const half8*)(lb + preoff[dx][0]);                \
                half8 b1 = *(const half8*)(lb + preoff[dx][1]);                \
                acc[rr][0][0] = __builtin_amdgcn_mfma_f32_32x32x16_f16(a0, b0, acc[rr][0][0], 0, 0, 0); \
                acc[rr][0][1] = __builtin_amdgcn_mfma_f32_32x32x16_f16(a0, b1, acc[rr][0][1], 0, 0, 0); \
                acc[rr][1][0] = __builtin_amdgcn_mfma_f32_32x32x16_f16(a1, b0, acc[rr][1][0], 0, 0, 0); \
                acc[rr][1][1] = __builtin_amdgcn_mfma_f32_32x32x16_f16(a1, b1, acc[rr][1][1], 0, 0, 0); \
            }                                                                  \
        }                                                                      \
        __builtin_amdgcn_s_setprio(0);                                         \
    }

    STAGE(0, actb0, wtb0);
    __syncthreads();                       // phase-0 buffers ready

    STAGE(1, actb1, wtb1);                 // in flight during compute(0)
    __builtin_amdgcn_sched_barrier(0);
    COMPUTE(actb0, wtb0);
    __syncthreads();                       // drains stage(1)

    STAGE(2, actb0, wtb0);
    __builtin_amdgcn_sched_barrier(0);
    COMPUTE(actb1, wtb1);
    __syncthreads();                       // drains stage(2)

    STAGE(3, actb1, wtb1);
    __builtin_amdgcn_sched_barrier(0);
    COMPUTE(actb0, wtb0);
    __syncthreads();                       // drains stage(3)

    COMPUTE(actb1, wtb1);
#undef STAGE
#undef COMPUTE

    // ---- epilogue: bias + ReLU -> chunk-plane f16 interior ----
    int m = sel[t * LL + layer];
    m = __builtin_amdgcn_readfirstlane(m);
    const float* Bp = enc_b + ((size_t)layer * MM + m) * CC;
#pragma unroll
    for (int rr = 0; rr < 2; ++rr) {
#pragma unroll
        for (int o = 0; o < 2; ++o)
#pragma unroll
            for (int j = 0; j < 2; ++j) {
                int px = px0 + j * 32 + n;
                size_t pxi = (size_t)(y0 + 2 * w + rr + 1) * PW + px + 1;
#pragma unroll
                for (int rg = 0; rg < 4; ++rg) {
                    int oci = 4 * ksub + 8 * rg;          // 0..28
                    int pl  = o * 2 + (oci >> 4);
                    _Float16* po = outp + (size_t)pl * CHP + pxi * 16 + (oci & 15);
                    half4 h;
#pragma unroll
                    for (int k = 0; k < 4; ++k)
                        h[k] = (_Float16)fmaxf(acc[rr][o][j][rg * 4 + k]
                                               + Bp[o * 32 + oci + k], 0.f);
                    *(half4*)po = h;
                }
            }
    }
}

// ---------------------------------------------------------------------------
// Decoder: 1x1 conv 64 -> 3 (+bias), L2-normalize task 2. Chunk-plane input.
// ---------------------------------------------------------------------------
__global__ __launch_bounds__(256) void decoder_kernel(
    const _Float16* __restrict__ in, // chunked padded, per-task stride ts halves
    size_t ts,
    const float* __restrict__ dec_w, // [T][3][64]
    const float* __restrict__ dec_b, // [T][3]
    float* __restrict__ out,         // [T][B][3][H][W]
    int task0, int ntask)
{
    const int HW = HH * WW;
    int gid = blockIdx.x * 256 + threadIdx.x;
    if (gid >= ntask * BB * HW) return;
    int tz = gid / (BB * HW);
    int rem = gid - tz * (BB * HW);
    int b = rem / HW;
    int px = rem - b * HW;
    int t = task0 + tz;
    int y = px >> 7;
    int xx = px & 127;

    const _Float16* base = in + (size_t)tz * ts + (size_t)b * IMGH;
    size_t pxi = ((size_t)(y + 1) * PW + xx + 1) * 16;
    const float* w = dec_w + (size_t)t * 3 * CC;

    float a0 = dec_b[t * 3 + 0];
    float a1 = dec_b[t * 3 + 1];
    float a2 = dec_b[t * 3 + 2];
#pragma unroll
    for (int il = 0; il < 4; ++il) {
        const _Float16* hp = base + (size_t)il * CHP + pxi;
#pragma unroll
        for (int cc = 0; cc < 16; cc += 8) {
            half8 h = *(const half8*)(hp + cc);
#pragma unroll
            for (int k = 0; k < 8; ++k) {
                float v = (float)h[k];
                int ch = il * 16 + cc + k;
                a0 += v * w[ch];
                a1 += v * w[CC + ch];
                a2 += v * w[2 * CC + ch];
            }
        }
    }
    if (t == 2) {
        float r = 1.0f / sqrtf(a0 * a0 + a1 * a1 + a2 * a2);
        a0 *= r; a1 *= r; a2 *= r;
    }
    float* ob = out + ((size_t)t * BB + b) * 3 * HW + px;
    ob[0]      = a0;
    ob[HW]     = a1;
    ob[2 * HW] = a2;
}

extern "C" void kernel_launch(void* const* d_in, const int* in_sizes, int n_in,
                              void* d_out, int out_size, void* d_ws, size_t ws_size,
                              hipStream_t stream) {
    const float* x      = (const float*)d_in[0];
    const float* alpha0 = (const float*)d_in[1];
    const float* alphas = (const float*)d_in[2];
    const float* g0     = (const float*)d_in[3];
    const float* gs     = (const float*)d_in[4];
    const float* enc_w  = (const float*)d_in[5];
    const float* enc_b  = (const float*)d_in[6];
    const float* dec_w  = (const float*)d_in[7];
    const float* dec_b  = (const float*)d_in[8];
    float* out = (float*)d_out;

    const size_t ACT = (size_t)BB * IMGH;      // halves per padded activation buffer
    char* pw = (char*)d_ws;
    int* sel = (int*)pw;                 pw += 1024;
    _Float16* W3 = (_Float16*)pw;        pw += (size_t)12 * 36864 * 2;
    _Float16* act0 = (_Float16*)pw;      pw += ACT * 2;
    _Float16* bufs = (_Float16*)pw;
    size_t base = (size_t)(pw - (char*)d_ws);
    bool fused = ws_size >= base + 6 * ACT * 2;

    prep_weights<<<dim3(36, 12), 256, 0, stream>>>(enc_w, alpha0, alphas, g0, gs, sel, W3);
    int nbuf = fused ? 7 : 3;
    zero_borders<<<dim3(nbuf * BB, 4), 256, 0, stream>>>(act0);
    to_chunked<<<dim3(2, HH, BB), 256, 0, stream>>>(x, act0);

    if (fused) {
        _Float16* A = bufs;        // task stride 2*ACT
        _Float16* B = bufs + ACT;  // task stride 2*ACT
        size_t ts = 2 * ACT;
        conv3x3_mfma<<<dim3(32, BB, 3), 256, 0, stream>>>(act0, A, W3, enc_b, sel, 0, 0, 0,  ts);
        conv3x3_mfma<<<dim3(32, BB, 3), 256, 0, stream>>>(A,    B, W3, enc_b, sel, 1, 0, ts, ts);
        conv3x3_mfma<<<dim3(32, BB, 3), 256, 0, stream>>>(B,    A, W3, enc_b, sel, 2, 0, ts, ts);
        conv3x3_mfma<<<dim3(32, BB, 3), 256, 0, stream>>>(A,    B, W3, enc_b, sel, 3, 0, ts, ts);
        decoder_kernel<<<(3 * BB * HH * WW + 255) / 256, 256, 0, stream>>>(
            B, ts, dec_w, dec_b, out, 0, 3);
    } else {
        _Float16* A = bufs;
        _Float16* B = bufs + ACT;
        for (int t = 0; t < TT; ++t) {
            conv3x3_mfma<<<dim3(32, BB, 1), 256, 0, stream>>>(act0, A, W3, enc_b, sel, 0, t, 0, 0);
            conv3x3_mfma<<<dim3(32, BB, 1), 256, 0, stream>>>(A,    B, W3, enc_b, sel, 1, t, 0, 0);
            conv3x3_mfma<<<dim3(32, BB, 1), 256, 0, stream>>>(B,    A, W3, enc_b, sel, 2, t, 0, 0);
            conv3x3_mfma<<<dim3(32, BB, 1), 256, 0, stream>>>(A,    B, W3, enc_b, sel, 3, t, 0, 0);
            decoder_kernel<<<(BB * HH * WW + 255) / 256, 256, 0, stream>>>(
                B, 0, dec_w, dec_b, out, t, 1);
        }
    }
}